// Round 1
// baseline (1175.032 us; speedup 1.0000x reference)
//
#include <hip/hip_runtime.h>
#include <hip/hip_bf16.h>
#include <cstdint>

typedef __attribute__((ext_vector_type(8))) short short8;
typedef __attribute__((ext_vector_type(4))) float floatx4;

#define NB 64
#define MM 4096
#define ND 256
#define NSLOT 16
#define RTOT 262144   // NB*MM
#define SCALE_F 0.0625f
#define LN_EPS_F 1e-5f

__device__ __forceinline__ unsigned short f32_to_bf16(float f) {
    union { float f; unsigned int u; } v; v.f = f;
    unsigned int u = v.u;
    return (unsigned short)((u + 0x7FFFu + ((u >> 16) & 1u)) >> 16);
}
__device__ __forceinline__ float bf_lo(unsigned int u){ union{unsigned int x; float f;} v; v.x = u << 16; return v.f; }
__device__ __forceinline__ float bf_hi(unsigned int u){ union{unsigned int x; float f;} v; v.x = u & 0xFFFF0000u; return v.f; }

// ---------------- prep: slot init + transposed bf16 weight [c][k] for k/v proj ----------------
__global__ __launch_bounds__(256) void k_prep(const float* __restrict__ noise,
        const float* __restrict__ mu, const float* __restrict__ lsig,
        const float* __restrict__ Wk, const float* __restrict__ Wv,
        float* __restrict__ slots, unsigned short* __restrict__ w_t) {
    int i = blockIdx.x * 256 + threadIdx.x;
    if (i < NB*NSLOT*ND) {
        int d = i & 255;
        slots[i] = mu[d] + expf(lsig[d]) * noise[i];
    }
    int j = i - NB*NSLOT*ND;
    if (j >= 0 && j < 512*256) {
        int c = j >> 8, kk = j & 255;
        float w = (c < 256) ? Wk[kk*256 + c] : Wv[kk*256 + (c - 256)];
        w_t[j] = f32_to_bf16(w);   // w_t[c][k]
    }
}

// ---------------- k/v projection: C[r, 0:512] = X[r,:] @ [Wk|Wv]; bf16 MFMA ----------------
// block: 512 thr (8 waves), tile 128 rows x 512 cols, K=256 in two halves of 128.
// LDS: A half [128][128] bf16 (32KB, XOR-swizzled) + B tile [128c][128k] (32KB).
__global__ __launch_bounds__(512) void k_gemm_kv(const float* __restrict__ X,
        const unsigned short* __restrict__ w_t,
        unsigned short* __restrict__ kbf, unsigned short* __restrict__ vbf) {
    __shared__ __align__(16) unsigned char lds[65536];
    const int tid = threadIdx.x;
    const int lane = tid & 63;
    const int wid = tid >> 6;
    const int wr = wid >> 2;     // 0..1 -> 64-row half
    const int wc = wid & 3;      // 0..3 -> 32-col strip
    const long rb = blockIdx.x;  // 0..2047

    floatx4 acc[4][4][2];
    #pragma unroll
    for (int cb = 0; cb < 4; cb++)
        #pragma unroll
        for (int m = 0; m < 4; m++)
            #pragma unroll
            for (int n = 0; n < 2; n++)
                acc[cb][m][n] = (floatx4){0.f, 0.f, 0.f, 0.f};

    #pragma unroll
    for (int kh = 0; kh < 2; kh++) {
        __syncthreads();                       // previous compute done before A overwrite
        // stage A half: rows 0..127, k kh*128..+127, fp32 -> bf16, swizzled
        #pragma unroll
        for (int it = 0; it < 4; it++) {
            int gid = tid + it * 512;          // 2048 granules of 8 bf16
            int row = gid >> 4, g = gid & 15;
            const float* src = X + (rb * 128 + row) * 256 + kh * 128 + g * 8;
            float4 f0 = *reinterpret_cast<const float4*>(src);
            float4 f1 = *reinterpret_cast<const float4*>(src + 4);
            unsigned int p0 = (unsigned int)f32_to_bf16(f0.x) | ((unsigned int)f32_to_bf16(f0.y) << 16);
            unsigned int p1 = (unsigned int)f32_to_bf16(f0.z) | ((unsigned int)f32_to_bf16(f0.w) << 16);
            unsigned int p2 = (unsigned int)f32_to_bf16(f1.x) | ((unsigned int)f32_to_bf16(f1.y) << 16);
            unsigned int p3 = (unsigned int)f32_to_bf16(f1.z) | ((unsigned int)f32_to_bf16(f1.w) << 16);
            int off = row * 256 + ((g * 16) ^ ((row & 7) << 4));
            uint4 val; val.x = p0; val.y = p1; val.z = p2; val.w = p3;
            *reinterpret_cast<uint4*>(&lds[off]) = val;
        }
        #pragma unroll
        for (int cb = 0; cb < 4; cb++) {
            __syncthreads();                   // A visible (cb=0) / prev B reads done
            #pragma unroll
            for (int it = 0; it < 4; it++) {
                int gid = tid + it * 512;
                int row = gid >> 4, g = gid & 15;
                const unsigned short* src = w_t + (cb * 128 + row) * 256 + kh * 128 + g * 8;
                uint4 val = *reinterpret_cast<const uint4*>(src);
                int off = 32768 + row * 256 + ((g * 16) ^ ((row & 7) << 4));
                *reinterpret_cast<uint4*>(&lds[off]) = val;
            }
            __syncthreads();
            #pragma unroll
            for (int ks = 0; ks < 4; ks++) {
                short8 a[4], bfr[2];
                int ga = ks * 4 + (lane >> 4);
                #pragma unroll
                for (int m = 0; m < 4; m++) {
                    int row = wr * 64 + m * 16 + (lane & 15);
                    int off = row * 256 + ((ga * 16) ^ ((row & 7) << 4));
                    a[m] = *reinterpret_cast<const short8*>(&lds[off]);
                }
                #pragma unroll
                for (int n = 0; n < 2; n++) {
                    int brow = wc * 32 + n * 16 + (lane & 15);
                    int off = 32768 + brow * 256 + ((ga * 16) ^ ((brow & 7) << 4));
                    bfr[n] = *reinterpret_cast<const short8*>(&lds[off]);
                }
                #pragma unroll
                for (int m = 0; m < 4; m++)
                    #pragma unroll
                    for (int n = 0; n < 2; n++)
                        acc[cb][m][n] = __builtin_amdgcn_mfma_f32_16x16x32_bf16(a[m], bfr[n], acc[cb][m][n], 0, 0, 0);
            }
        }
    }
    // epilogue: C layout col=lane&15, row=(lane>>4)*4+reg
    #pragma unroll
    for (int cb = 0; cb < 4; cb++)
        #pragma unroll
        for (int m = 0; m < 4; m++)
            #pragma unroll
            for (int n = 0; n < 2; n++)
                #pragma unroll
                for (int r = 0; r < 4; r++) {
                    long row_g = rb * 128 + wr * 64 + m * 16 + (lane >> 4) * 4 + r;
                    int c = cb * 128 + wc * 32 + n * 16 + (lane & 15);
                    unsigned short hv = f32_to_bf16(acc[cb][m][n][r]);
                    if (c < 256) kbf[row_g * 256 + c] = hv;
                    else         vbf[row_g * 256 + (c - 256)] = hv;
                }
}

// ---------------- q = SCALE * slots @ Wq (fp32) ----------------
__global__ __launch_bounds__(256) void k_qproj(const float* __restrict__ slots,
        const float* __restrict__ Wq, float* __restrict__ q) {
    __shared__ float s_lds[256];
    int row = blockIdx.x, t = threadIdx.x;
    s_lds[t] = slots[(long)row * 256 + t];
    __syncthreads();
    float a0 = 0.f, a1 = 0.f, a2 = 0.f, a3 = 0.f;
    #pragma unroll 4
    for (int d = 0; d < 256; d += 4) {
        a0 += s_lds[d]     * Wq[(d)     * 256 + t];
        a1 += s_lds[d + 1] * Wq[(d + 1) * 256 + t];
        a2 += s_lds[d + 2] * Wq[(d + 2) * 256 + t];
        a3 += s_lds[d + 3] * Wq[(d + 3) * 256 + t];
    }
    q[(long)row * 256 + t] = (a0 + a1 + a2 + a3) * SCALE_F;
}

// ---------------- logits[b,n,m] = q[b,n,:] . k[b,m,:] (VALU, bf16 k) ----------------
__global__ __launch_bounds__(256) void k_logits(const float* __restrict__ q,
        const unsigned short* __restrict__ kbf, float* __restrict__ logits) {
    __shared__ float q_lds[16 * 256];
    int b = blockIdx.y, mc = blockIdx.x, t = threadIdx.x;
    #pragma unroll
    for (int it = 0; it < 4; it++) {
        int gid = t + it * 256;
        *reinterpret_cast<float4*>(&q_lds[gid * 4]) =
            *reinterpret_cast<const float4*>(&q[(long)b * 4096 + gid * 4]);
    }
    __syncthreads();
    int ml = t & 63, ng = t >> 6;
    float acc[4][4];
    #pragma unroll
    for (int i = 0; i < 4; i++)
        #pragma unroll
        for (int j = 0; j < 4; j++) acc[i][j] = 0.f;
    const unsigned short* kb = kbf + ((long)b * 4096 + mc * 256 + ml) * 256;
    for (int d0 = 0; d0 < 256; d0 += 8) {
        float kf[4][8];
        #pragma unroll
        for (int i = 0; i < 4; i++) {
            uint4 uv = *reinterpret_cast<const uint4*>(kb + (long)i * 64 * 256 + d0);
            kf[i][0] = bf_lo(uv.x); kf[i][1] = bf_hi(uv.x);
            kf[i][2] = bf_lo(uv.y); kf[i][3] = bf_hi(uv.y);
            kf[i][4] = bf_lo(uv.z); kf[i][5] = bf_hi(uv.z);
            kf[i][6] = bf_lo(uv.w); kf[i][7] = bf_hi(uv.w);
        }
        #pragma unroll
        for (int j = 0; j < 4; j++) {
            const float* qp = &q_lds[(ng * 4 + j) * 256 + d0];
            float4 qa = *reinterpret_cast<const float4*>(qp);
            float4 qb = *reinterpret_cast<const float4*>(qp + 4);
            #pragma unroll
            for (int i = 0; i < 4; i++) {
                acc[i][j] += qa.x * kf[i][0] + qa.y * kf[i][1] + qa.z * kf[i][2] + qa.w * kf[i][3]
                           + qb.x * kf[i][4] + qb.y * kf[i][5] + qb.z * kf[i][6] + qb.w * kf[i][7];
            }
        }
    }
    #pragma unroll
    for (int j = 0; j < 4; j++)
        #pragma unroll
        for (int i = 0; i < 4; i++)
            logits[((long)b * 16 + ng * 4 + j) * 4096 + mc * 256 + i * 64 + ml] = acc[i][j];
}

// ---------------- row softmax over M=4096, write bf16 probs ----------------
__global__ __launch_bounds__(256) void k_softmax(const float* __restrict__ logits,
        unsigned short* __restrict__ attn) {
    __shared__ float red[8];
    long base = (long)blockIdx.x * 4096;
    int t = threadIdx.x;
    float v[16];
    #pragma unroll
    for (int it = 0; it < 4; it++) {
        float4 f = *reinterpret_cast<const float4*>(&logits[base + t * 16 + it * 4]);
        v[it * 4] = f.x; v[it * 4 + 1] = f.y; v[it * 4 + 2] = f.z; v[it * 4 + 3] = f.w;
    }
    float mx = v[0];
    #pragma unroll
    for (int j = 1; j < 16; j++) mx = fmaxf(mx, v[j]);
    #pragma unroll
    for (int off = 32; off > 0; off >>= 1) mx = fmaxf(mx, __shfl_xor(mx, off));
    if ((t & 63) == 0) red[t >> 6] = mx;
    __syncthreads();
    mx = fmaxf(fmaxf(red[0], red[1]), fmaxf(red[2], red[3]));
    float e[16]; float s = 0.f;
    #pragma unroll
    for (int j = 0; j < 16; j++) { e[j] = expf(v[j] - mx); s += e[j]; }
    #pragma unroll
    for (int off = 32; off > 0; off >>= 1) s += __shfl_xor(s, off);
    if ((t & 63) == 0) red[4 + (t >> 6)] = s;
    __syncthreads();
    s = red[4] + red[5] + red[6] + red[7];
    float inv = 1.f / s;
    unsigned short h[16];
    #pragma unroll
    for (int j = 0; j < 16; j++) h[j] = f32_to_bf16(e[j] * inv);
    uint4 o0, o1;
    o0.x = h[0] | ((unsigned)h[1] << 16);  o0.y = h[2] | ((unsigned)h[3] << 16);
    o0.z = h[4] | ((unsigned)h[5] << 16);  o0.w = h[6] | ((unsigned)h[7] << 16);
    o1.x = h[8] | ((unsigned)h[9] << 16);  o1.y = h[10] | ((unsigned)h[11] << 16);
    o1.z = h[12] | ((unsigned)h[13] << 16); o1.w = h[14] | ((unsigned)h[15] << 16);
    *reinterpret_cast<uint4*>(&attn[base + t * 16]) = o0;
    *reinterpret_cast<uint4*>(&attn[base + t * 16 + 8]) = o1;
}

// ---------------- partial PV: part[b,mc,n,:] = attn[b,n,mc*512..] @ v[b,mc*512..,:] ----------------
__global__ __launch_bounds__(256) void k_pv(const unsigned short* __restrict__ attn,
        const unsigned short* __restrict__ vbf, float* __restrict__ part) {
    __shared__ float p_lds[512 * 16];            // [m'][n] transposed, 32KB
    __shared__ unsigned short v_lds[64 * 256];   // 32KB
    int b = blockIdx.y, mc = blockIdx.x, t = threadIdx.x;
    // stage P transposed (bf16 -> f32)
    #pragma unroll
    for (int it = 0; it < 4; it++) {
        int gid = t + it * 256;                  // 1024 granules of 8
        int n = gid >> 6, g = gid & 63;
        uint4 u = *reinterpret_cast<const uint4*>(&attn[((long)b * 16 + n) * 4096 + mc * 512 + g * 8]);
        int m0 = g * 8;
        p_lds[(m0 + 0) * 16 + n] = bf_lo(u.x); p_lds[(m0 + 1) * 16 + n] = bf_hi(u.x);
        p_lds[(m0 + 2) * 16 + n] = bf_lo(u.y); p_lds[(m0 + 3) * 16 + n] = bf_hi(u.y);
        p_lds[(m0 + 4) * 16 + n] = bf_lo(u.z); p_lds[(m0 + 5) * 16 + n] = bf_hi(u.z);
        p_lds[(m0 + 6) * 16 + n] = bf_lo(u.w); p_lds[(m0 + 7) * 16 + n] = bf_hi(u.w);
    }
    int n = t & 15, db = t >> 4;   // thread: slot n, d-range db*16..+15
    float acc[16];
    #pragma unroll
    for (int j = 0; j < 16; j++) acc[j] = 0.f;
    for (int msc = 0; msc < 8; msc++) {
        __syncthreads();
        #pragma unroll
        for (int it = 0; it < 8; it++) {
            int gid = t + it * 256;
            int row = gid >> 5, g = gid & 31;
            *reinterpret_cast<uint4*>(&v_lds[row * 256 + g * 8]) =
                *reinterpret_cast<const uint4*>(&vbf[((long)b * 4096 + mc * 512 + msc * 64 + row) * 256 + g * 8]);
        }
        __syncthreads();
        #pragma unroll 2
        for (int mi = 0; mi < 64; mi++) {
            float p = p_lds[(msc * 64 + mi) * 16 + n];
            const unsigned short* vr = &v_lds[mi * 256 + db * 16];
            uint4 u0 = *reinterpret_cast<const uint4*>(vr);
            uint4 u1 = *reinterpret_cast<const uint4*>(vr + 8);
            acc[0]  += p * bf_lo(u0.x); acc[1]  += p * bf_hi(u0.x);
            acc[2]  += p * bf_lo(u0.y); acc[3]  += p * bf_hi(u0.y);
            acc[4]  += p * bf_lo(u0.z); acc[5]  += p * bf_hi(u0.z);
            acc[6]  += p * bf_lo(u0.w); acc[7]  += p * bf_hi(u0.w);
            acc[8]  += p * bf_lo(u1.x); acc[9]  += p * bf_hi(u1.x);
            acc[10] += p * bf_lo(u1.y); acc[11] += p * bf_hi(u1.y);
            acc[12] += p * bf_lo(u1.z); acc[13] += p * bf_hi(u1.z);
            acc[14] += p * bf_lo(u1.w); acc[15] += p * bf_hi(u1.w);
        }
    }
    long o = (((long)b * 8 + mc) * 16 + n) * 256 + db * 16;
    #pragma unroll
    for (int j = 0; j < 16; j += 4) {
        float4 f; f.x = acc[j]; f.y = acc[j + 1]; f.z = acc[j + 2]; f.w = acc[j + 3];
        *reinterpret_cast<float4*>(&part[o + j]) = f;
    }
}

// ---------------- fused GRU + LayerNorm + MLP residual; 4 rows per block ----------------
__global__ __launch_bounds__(256) void k_gru(const float* __restrict__ part,
        float* __restrict__ slots,
        const float* __restrict__ W_ih, const float* __restrict__ W_hh,
        const float* __restrict__ b_ih, const float* __restrict__ b_hh,
        const float* __restrict__ ln_g, const float* __restrict__ ln_b,
        const float* __restrict__ W1, const float* __restrict__ b1,
        const float* __restrict__ W2, const float* __restrict__ b2) {
    __shared__ float u_lds[4][256], s_lds[4][256], h_lds[4][256], hm_lds[4][512];
    __shared__ float red[4][4][2];
    int blk = blockIdx.x, t = threadIdx.x;
    int row0 = blk * 4;
    int b = row0 >> 4, n0 = row0 & 15;
    #pragma unroll
    for (int rr = 0; rr < 4; rr++) {
        float s = 0.f;
        #pragma unroll
        for (int c = 0; c < 8; c++)
            s += part[(((long)b * 8 + c) * 16 + (n0 + rr)) * 256 + t];
        u_lds[rr][t] = s;
        s_lds[rr][t] = slots[(long)(row0 + rr) * 256 + t];
    }
    __syncthreads();
    float gxr[4] = {0,0,0,0}, gxz[4] = {0,0,0,0}, gxn[4] = {0,0,0,0};
    float ghr[4] = {0,0,0,0}, ghz[4] = {0,0,0,0}, ghn[4] = {0,0,0,0};
    #pragma unroll 4
    for (int d = 0; d < 256; d++) {
        float wr0 = W_ih[d * 768 + t], wz0 = W_ih[d * 768 + t + 256], wn0 = W_ih[d * 768 + t + 512];
        float vr0 = W_hh[d * 768 + t], vz0 = W_hh[d * 768 + t + 256], vn0 = W_hh[d * 768 + t + 512];
        #pragma unroll
        for (int rr = 0; rr < 4; rr++) {
            float ud = u_lds[rr][d], sd = s_lds[rr][d];
            gxr[rr] += ud * wr0; gxz[rr] += ud * wz0; gxn[rr] += ud * wn0;
            ghr[rr] += sd * vr0; ghz[rr] += sd * vz0; ghn[rr] += sd * vn0;
        }
    }
    float bir = b_ih[t], biz = b_ih[t + 256], bin = b_ih[t + 512];
    float bhr = b_hh[t], bhz = b_hh[t + 256], bhn = b_hh[t + 512];
    float snew[4];
    int wv = t >> 6, ln = t & 63;
    #pragma unroll
    for (int rr = 0; rr < 4; rr++) {
        float r = 1.f / (1.f + expf(-(gxr[rr] + bir + ghr[rr] + bhr)));
        float z = 1.f / (1.f + expf(-(gxz[rr] + biz + ghz[rr] + bhz)));
        float nn = tanhf(gxn[rr] + bin + r * (ghn[rr] + bhn));
        snew[rr] = (1.f - z) * nn + z * s_lds[rr][t];
        float sm = snew[rr], sq = snew[rr] * snew[rr];
        #pragma unroll
        for (int off = 32; off > 0; off >>= 1) { sm += __shfl_xor(sm, off); sq += __shfl_xor(sq, off); }
        if (ln == 0) { red[wv][rr][0] = sm; red[wv][rr][1] = sq; }
    }
    __syncthreads();
    float lng = ln_g[t], lnb = ln_b[t];
    #pragma unroll
    for (int rr = 0; rr < 4; rr++) {
        float sm = red[0][rr][0] + red[1][rr][0] + red[2][rr][0] + red[3][rr][0];
        float sq = red[0][rr][1] + red[1][rr][1] + red[2][rr][1] + red[3][rr][1];
        float mu = sm * (1.f / 256.f);
        float var = sq * (1.f / 256.f) - mu * mu;
        float rs = rsqrtf(var + LN_EPS_F);
        h_lds[rr][t] = (snew[rr] - mu) * rs * lng + lnb;
    }
    __syncthreads();
    float m1a[4] = {0,0,0,0}, m1b[4] = {0,0,0,0};
    #pragma unroll 4
    for (int d = 0; d < 256; d++) {
        float wa = W1[d * 512 + t], wb = W1[d * 512 + t + 256];
        #pragma unroll
        for (int rr = 0; rr < 4; rr++) { float hd = h_lds[rr][d]; m1a[rr] += hd * wa; m1b[rr] += hd * wb; }
    }
    float b1a = b1[t], b1b = b1[t + 256];
    #pragma unroll
    for (int rr = 0; rr < 4; rr++) {
        float xa = m1a[rr] + b1a, xb = m1b[rr] + b1b;
        hm_lds[rr][t]       = 0.5f * xa * (1.f + erff(xa * 0.70710678118654752f));
        hm_lds[rr][t + 256] = 0.5f * xb * (1.f + erff(xb * 0.70710678118654752f));
    }
    __syncthreads();
    float m2[4] = {0,0,0,0};
    #pragma unroll 4
    for (int d = 0; d < 512; d++) {
        float w2v = W2[d * 256 + t];
        #pragma unroll
        for (int rr = 0; rr < 4; rr++) m2[rr] += hm_lds[rr][d] * w2v;
    }
    float b2v = b2[t];
    #pragma unroll
    for (int rr = 0; rr < 4; rr++)
        slots[(long)(row0 + rr) * 256 + t] = snew[rr] + m2[rr] + b2v;
}

extern "C" void kernel_launch(void* const* d_in, const int* in_sizes, int n_in,
                              void* d_out, int out_size, void* d_ws, size_t ws_size,
                              hipStream_t stream) {
    const float* inputs  = (const float*)d_in[0];
    const float* noise   = (const float*)d_in[1];
    const float* slot_mu = (const float*)d_in[2];
    const float* slot_ls = (const float*)d_in[3];
    const float* Wq   = (const float*)d_in[4];
    const float* Wk   = (const float*)d_in[5];
    const float* Wv   = (const float*)d_in[6];
    const float* W_ih = (const float*)d_in[7];
    const float* W_hh = (const float*)d_in[8];
    const float* b_ih = (const float*)d_in[9];
    const float* b_hh = (const float*)d_in[10];
    const float* ln_g = (const float*)d_in[11];
    const float* ln_b = (const float*)d_in[12];
    const float* W1   = (const float*)d_in[13];
    const float* b1   = (const float*)d_in[14];
    const float* W2   = (const float*)d_in[15];
    const float* b2   = (const float*)d_in[16];
    float* slots = (float*)d_out;

    char* ws = (char*)d_ws;
    unsigned short* kbf   = (unsigned short*)(ws);                 // 134217728 B
    unsigned short* vbf   = (unsigned short*)(ws + 134217728);     // 134217728 B
    float*          logits= (float*)         (ws + 268435456);     // 16777216 B
    unsigned short* attn  = (unsigned short*)(ws + 285212672);     // 8388608 B
    float*          q     = (float*)         (ws + 293601280);     // 1048576 B
    float*          part  = (float*)         (ws + 294649856);     // 8388608 B
    unsigned short* w_t   = (unsigned short*)(ws + 303038464);     // 262144 B

    k_prep<<<dim3(1536), dim3(256), 0, stream>>>(noise, slot_mu, slot_ls, Wk, Wv, slots, w_t);
    k_gemm_kv<<<dim3(2048), dim3(512), 0, stream>>>(inputs, w_t, kbf, vbf);
    for (int it = 0; it < 3; it++) {
        k_qproj<<<dim3(1024), dim3(256), 0, stream>>>(slots, Wq, q);
        k_logits<<<dim3(16, 64), dim3(256), 0, stream>>>(q, kbf, logits);
        k_softmax<<<dim3(1024), dim3(256), 0, stream>>>(logits, attn);
        k_pv<<<dim3(8, 64), dim3(256), 0, stream>>>(attn, vbf, part);
        k_gru<<<dim3(256), dim3(256), 0, stream>>>(part, slots,
                W_ih, W_hh, b_ih, b_hh, ln_g, ln_b, W1, b1, W2, b2);
    }
}

// Round 2
// 883.723 us; speedup vs baseline: 1.3296x; 1.3296x over previous
//
#include <hip/hip_runtime.h>
#include <hip/hip_bf16.h>
#include <cstdint>

typedef __attribute__((ext_vector_type(8))) short short8;
typedef __attribute__((ext_vector_type(4))) float floatx4;
typedef unsigned short u16;
typedef unsigned int u32;

#define SCALE_F 0.0625f
#define LN_EPS_F 1e-5f
#define NEG_BIG (-3.0e38f)

__device__ __forceinline__ u16 f32_to_bf16(float f) {
    union { float f; u32 u; } v; v.f = f;
    u32 u = v.u;
    return (u16)((u + 0x7FFFu + ((u >> 16) & 1u)) >> 16);
}
__device__ __forceinline__ float bf_lo(u32 u){ union{u32 x; float f;} v; v.x = u << 16; return v.f; }
__device__ __forceinline__ float bf_hi(u32 u){ union{u32 x; float f;} v; v.x = u & 0xFFFF0000u; return v.f; }
// RNE pack of two f32 -> two bf16 in one instr
__device__ __forceinline__ u32 cvt_pk2(float lo, float hi) {
    u32 r; asm volatile("v_cvt_pk_bf16_f32 %0, %1, %2" : "=v"(r) : "v"(lo), "v"(hi)); return r;
}
// async global->LDS, 16B per lane; ldst must be wave-uniform base (lane*16 added by HW)
__device__ __forceinline__ void gload16(const void* gsrc, void* ldst) {
    __builtin_amdgcn_global_load_lds((const __attribute__((address_space(1))) u32*)gsrc,
                                     (__attribute__((address_space(3))) u32*)ldst, 16, 0, 0);
}

// ---------------- prep: slot init + all weight repacks ----------------
// w_t[c][k] bf16 (c in 0..511 = Wk|Wv cols); wqp/wgh/w1p/w2p = bf16-pair packed u32
__global__ __launch_bounds__(256) void k_prep(
        const float* __restrict__ noise, const float* __restrict__ mu, const float* __restrict__ lsig,
        const float* __restrict__ Wq, const float* __restrict__ Wk, const float* __restrict__ Wv,
        const float* __restrict__ W_ih, const float* __restrict__ W_hh,
        const float* __restrict__ W1, const float* __restrict__ W2,
        float* __restrict__ slots, u16* __restrict__ w_t,
        u32* __restrict__ wqp, u32* __restrict__ wgh, u32* __restrict__ w1p, u32* __restrict__ w2p) {
    int i = blockIdx.x * 256 + threadIdx.x;
    if (i < 262144) {
        int d = i & 255;
        slots[i] = mu[d] + expf(lsig[d]) * noise[i];
    } else if (i < 393216) {
        int j = i - 262144; int c = j >> 8, k = j & 255;
        float w = (c < 256) ? Wk[k*256 + c] : Wv[k*256 + (c - 256)];
        w_t[j] = f32_to_bf16(w);
    } else if (i < 425984) {
        int j = i - 393216; int d2 = j >> 8, t = j & 255;
        wqp[j] = cvt_pk2(Wq[(2*d2)*256 + t], Wq[(2*d2+1)*256 + t]);
    } else if (i < 622592) {
        int j = i - 425984;
        wgh[j] = cvt_pk2(W_ih[j], W_hh[j]);   // lo=W_ih, hi=W_hh, same [d][c] index
    } else if (i < 688128) {
        int j = i - 622592; int d = j >> 8, t = j & 255;
        w1p[j] = cvt_pk2(W1[d*512 + t], W1[d*512 + t + 256]);  // lo=col t, hi=col t+256
    } else if (i < 753664) {
        int j = i - 688128; int d2 = j >> 8, t = j & 255;
        w2p[j] = cvt_pk2(W2[(2*d2)*256 + t], W2[(2*d2+1)*256 + t]);  // lo=row 2d2, hi=row 2d2+1
    }
}

// ---------------- k/v projection GEMM: C[r,0:512] = X[r,:] @ [Wk|Wv] ----------------
// 512 thr / 8 waves, tile 128 rows x 512 cols, K=256 (2 halves of 128).
// A: VALU-staged fp32->bf16 swizzled; B: global_load_lds (linear dest, XOR'd per-lane src).
// MFMA operands SWAPPED: mfma(w_frag, x_frag) -> lane's 4 acc regs = 4 consecutive cols.
__global__ __launch_bounds__(512) void k_gemm_kv(const float* __restrict__ X,
        const u16* __restrict__ w_t, u16* __restrict__ kbf, u16* __restrict__ vbf) {
    __shared__ __align__(16) unsigned char lds[65536];
    const int tid = threadIdx.x;
    const int lane = tid & 63;
    const int wid = tid >> 6;
    const int wr = wid >> 2;     // 0..1 -> 64-row half
    const int wc = wid & 3;      // 0..3 -> 32-col strip
    const long rb = blockIdx.x;  // 0..2047

    floatx4 acc[4][4][2];        // [cb][m][n]
    #pragma unroll
    for (int cb = 0; cb < 4; cb++)
        #pragma unroll
        for (int m = 0; m < 4; m++)
            #pragma unroll
            for (int n = 0; n < 2; n++)
                acc[cb][m][n] = (floatx4){0.f, 0.f, 0.f, 0.f};

    #pragma unroll
    for (int kh = 0; kh < 2; kh++) {
        __syncthreads();
        // stage A half: rows 0..127, k kh*128..+127, fp32 -> bf16, XOR-swizzled
        #pragma unroll
        for (int it = 0; it < 4; it++) {
            int gid = tid + it * 512;
            int row = gid >> 4, g = gid & 15;
            const float* src = X + (rb * 128 + row) * 256 + kh * 128 + g * 8;
            float4 f0 = *reinterpret_cast<const float4*>(src);
            float4 f1 = *reinterpret_cast<const float4*>(src + 4);
            uint4 val;
            val.x = cvt_pk2(f0.x, f0.y); val.y = cvt_pk2(f0.z, f0.w);
            val.z = cvt_pk2(f1.x, f1.y); val.w = cvt_pk2(f1.z, f1.w);
            int off = row * 256 + ((g * 16) ^ ((row & 7) << 4));
            *reinterpret_cast<uint4*>(&lds[off]) = val;
        }
        #pragma unroll
        for (int cb = 0; cb < 4; cb++) {
            __syncthreads();   // prev B reads done (and A visible at cb=0)
            // stage B tile via global_load_lds: linear LDS dest, XOR'd source granule
            #pragma unroll
            for (int it = 0; it < 4; it++) {
                int gid = tid + it * 512;
                int brow = gid >> 4, gp = gid & 15;
                int glog = gp ^ (brow & 7);
                const u16* src = w_t + (cb * 128 + brow) * 256 + kh * 128 + glog * 8;
                gload16(src, &lds[32768 + it * 8192 + wid * 1024]);
            }
            __syncthreads();   // drains vmcnt -> B visible
            #pragma unroll
            for (int ks = 0; ks < 4; ks++) {
                short8 a[4], bfr[2];
                int ga = ks * 4 + (lane >> 4);
                #pragma unroll
                for (int m = 0; m < 4; m++) {
                    int row = wr * 64 + m * 16 + (lane & 15);
                    int off = row * 256 + ((ga * 16) ^ ((row & 7) << 4));
                    a[m] = *reinterpret_cast<const short8*>(&lds[off]);
                }
                #pragma unroll
                for (int n = 0; n < 2; n++) {
                    int brow = wc * 32 + n * 16 + (lane & 15);
                    int off = 32768 + brow * 256 + ((ga * 16) ^ ((brow & 7) << 4));
                    bfr[n] = *reinterpret_cast<const short8*>(&lds[off]);
                }
                #pragma unroll
                for (int m = 0; m < 4; m++)
                    #pragma unroll
                    for (int n = 0; n < 2; n++)
                        acc[cb][m][n] = __builtin_amdgcn_mfma_f32_16x16x32_bf16(bfr[n], a[m], acc[cb][m][n], 0, 0, 0);
            }
        }
    }
    // epilogue: C-row = w-col = (lane>>4)*4+reg (4 consecutive c!), C-col = x-row = lane&15
    const int cq = lane >> 4, nt = cq & 1, half = cq >> 1;
    #pragma unroll
    for (int cb = 0; cb < 4; cb++)
        #pragma unroll
        for (int m = 0; m < 4; m++) {
            u32 pn[2][2], po[2][2];
            #pragma unroll
            for (int n = 0; n < 2; n++) {
                pn[n][0] = cvt_pk2(acc[cb][m][n][0], acc[cb][m][n][1]);
                pn[n][1] = cvt_pk2(acc[cb][m][n][2], acc[cb][m][n][3]);
                po[n][0] = (u32)__shfl_xor((int)pn[n][0], 16);
                po[n][1] = (u32)__shfl_xor((int)pn[n][1], 16);
            }
            u32 a0 = pn[nt][0], a1 = pn[nt][1], b0 = po[nt][0], b1 = po[nt][1];
            uint4 qv;
            if (cq & 1) { qv.x = b0; qv.y = b1; qv.z = a0; qv.w = a1; }
            else        { qv.x = a0; qv.y = a1; qv.z = b0; qv.w = b1; }
            long row_g = rb * 128 + wr * 64 + m * 16 + (lane & 15);
            int c0 = cb * 128 + wc * 32 + nt * 16 + half * 8;
            if (c0 < 256) *reinterpret_cast<uint4*>(&kbf[row_g * 256 + c0]) = qv;
            else          *reinterpret_cast<uint4*>(&vbf[row_g * 256 + c0 - 256]) = qv;
        }
}

// ---------------- initial q = SCALE * slots @ Wq (bf16 packed weights) ----------------
__global__ __launch_bounds__(256) void k_qproj(const float* __restrict__ slots,
        const u32* __restrict__ wqp, float* __restrict__ q) {
    __shared__ float s_lds[256];
    int row = blockIdx.x, t = threadIdx.x;
    s_lds[t] = slots[(long)row * 256 + t];
    __syncthreads();
    float a = 0.f;
    #pragma unroll 8
    for (int d2 = 0; d2 < 128; d2++) {
        u32 w = wqp[d2 * 256 + t];
        a += bf_lo(w) * s_lds[2*d2] + bf_hi(w) * s_lds[2*d2 + 1];
    }
    q[(long)row * 256 + t] = a * SCALE_F;
}

// ---------------- fused flash attention: partial (m,l,acc) per (b, mc) ----------------
// 256 thr / 4 waves; wave w covers n in {4w..4w+3}; 16 m-tiles of 32 rows.
// dot phase: lane = m (l&31), np half -> 2 n's. PV phase: lane = d-slice (m*8), 2 n's.
__device__ __forceinline__ void flash_stage(const u16* __restrict__ kbf, const u16* __restrict__ vbf,
        long kv_base, int t, u16* k_lds, u16* v_lds, int tid, int w) {
    #pragma unroll
    for (int it = 0; it < 4; it++) {
        int gid = tid + it * 256;
        int r = gid >> 5, gp = gid & 31;
        int glog = gp ^ (r & 7);
        gload16(kbf + (kv_base + t * 32 + r) * 256 + glog * 8, &k_lds[it * 2048 + w * 512]);
        gload16(vbf + (kv_base + t * 32 + r) * 256 + gp * 8,   &v_lds[it * 2048 + w * 512]);
    }
}

__global__ __launch_bounds__(256) void k_flash(const float* __restrict__ q,
        const u16* __restrict__ kbf, const u16* __restrict__ vbf,
        float* __restrict__ part, float* __restrict__ ml) {
    __shared__ __align__(16) float q_lds[16 * 256];   // 16KB
    __shared__ __align__(16) u16 k_lds[32 * 256];     // 16KB, XOR-swizzled rows
    __shared__ __align__(16) u16 v_lds[32 * 256];     // 16KB, linear
    __shared__ float p_lds[4 * 32 * 4];               // [w][m][np*2+j], 2KB
    const int b = blockIdx.y, mc = blockIdx.x, tid = threadIdx.x;
    const int w = tid >> 6, l = tid & 63, m = l & 31, np = l >> 5;
    const int n_base = w * 4 + np * 2;
    #pragma unroll
    for (int it = 0; it < 4; it++) {
        int gid = tid + it * 256;
        *reinterpret_cast<float4*>(&q_lds[gid * 4]) =
            *reinterpret_cast<const float4*>(&q[(long)b * 4096 + gid * 4]);
    }
    const long kv_base = (long)b * 4096 + mc * 512;
    float mrun0 = NEG_BIG, mrun1 = NEG_BIG, lrun0 = 0.f, lrun1 = 0.f;
    float acc[16];
    #pragma unroll
    for (int k = 0; k < 16; k++) acc[k] = 0.f;
    const float* qp0 = &q_lds[n_base * 256];
    const float* qp1 = qp0 + 256;

    flash_stage(kbf, vbf, kv_base, 0, k_lds, v_lds, tid, w);
    __syncthreads();

    for (int t = 0; t < 16; t++) {
        // ---- QK^T for this lane's m-row, 2 n's ----
        float s0 = 0.f, s1 = 0.f;
        #pragma unroll 4
        for (int d0 = 0; d0 < 256; d0 += 8) {
            int off = m * 256 + ((d0 >> 3) * 8) ^ 0; // placeholder (computed below)
            off = m * 256 + ((((d0 >> 3) * 16) ^ ((m & 7) << 4)) >> 1);  // u16 index
            uint4 kv = *reinterpret_cast<const uint4*>(&k_lds[off]);
            float kf0 = bf_lo(kv.x), kf1 = bf_hi(kv.x), kf2 = bf_lo(kv.y), kf3 = bf_hi(kv.y);
            float kf4 = bf_lo(kv.z), kf5 = bf_hi(kv.z), kf6 = bf_lo(kv.w), kf7 = bf_hi(kv.w);
            float4 qa = *reinterpret_cast<const float4*>(qp0 + d0);
            float4 qb = *reinterpret_cast<const float4*>(qp0 + d0 + 4);
            float4 qc = *reinterpret_cast<const float4*>(qp1 + d0);
            float4 qd = *reinterpret_cast<const float4*>(qp1 + d0 + 4);
            s0 += qa.x*kf0 + qa.y*kf1 + qa.z*kf2 + qa.w*kf3 + qb.x*kf4 + qb.y*kf5 + qb.z*kf6 + qb.w*kf7;
            s1 += qc.x*kf0 + qc.y*kf1 + qc.z*kf2 + qc.w*kf3 + qd.x*kf4 + qd.y*kf5 + qd.z*kf6 + qd.w*kf7;
        }
        // ---- online softmax over this tile's 32 m (within 32-lane group) ----
        float mx0 = s0, mx1 = s1;
        #pragma unroll
        for (int off = 1; off <= 16; off <<= 1) {
            mx0 = fmaxf(mx0, __shfl_xor(mx0, off));
            mx1 = fmaxf(mx1, __shfl_xor(mx1, off));
        }
        float mn0 = fmaxf(mrun0, mx0), mn1 = fmaxf(mrun1, mx1);
        float sc0 = __expf(mrun0 - mn0), sc1 = __expf(mrun1 - mn1);
        float p0 = __expf(s0 - mn0), p1 = __expf(s1 - mn1);
        float ps0 = p0, ps1 = p1;
        #pragma unroll
        for (int off = 1; off <= 16; off <<= 1) {
            ps0 += __shfl_xor(ps0, off);
            ps1 += __shfl_xor(ps1, off);
        }
        lrun0 = lrun0 * sc0 + ps0; lrun1 = lrun1 * sc1 + ps1;
        mrun0 = mn0; mrun1 = mn1;
        #pragma unroll
        for (int k = 0; k < 8; k++) { acc[k] *= sc0; acc[8 + k] *= sc1; }
        p_lds[w * 128 + m * 4 + np * 2 + 0] = p0;
        p_lds[w * 128 + m * 4 + np * 2 + 1] = p1;
        asm volatile("s_waitcnt lgkmcnt(0)" ::: "memory");
        // ---- PV: lane = d-slice m*8..m*8+7 (np-dup reads broadcast) ----
        #pragma unroll 4
        for (int mi = 0; mi < 32; mi++) {
            float2 pp = *reinterpret_cast<const float2*>(&p_lds[w * 128 + mi * 4 + np * 2]);
            uint4 vv = *reinterpret_cast<const uint4*>(&v_lds[mi * 256 + m * 8]);
            float vf0 = bf_lo(vv.x), vf1 = bf_hi(vv.x), vf2 = bf_lo(vv.y), vf3 = bf_hi(vv.y);
            float vf4 = bf_lo(vv.z), vf5 = bf_hi(vv.z), vf6 = bf_lo(vv.w), vf7 = bf_hi(vv.w);
            acc[0] += pp.x*vf0; acc[1] += pp.x*vf1; acc[2] += pp.x*vf2; acc[3] += pp.x*vf3;
            acc[4] += pp.x*vf4; acc[5] += pp.x*vf5; acc[6] += pp.x*vf6; acc[7] += pp.x*vf7;
            acc[8] += pp.y*vf0; acc[9] += pp.y*vf1; acc[10]+= pp.y*vf2; acc[11]+= pp.y*vf3;
            acc[12]+= pp.y*vf4; acc[13]+= pp.y*vf5; acc[14]+= pp.y*vf6; acc[15]+= pp.y*vf7;
        }
        __syncthreads();                   // all waves done reading k/v of tile t
        if (t < 15) flash_stage(kbf, vbf, kv_base, t + 1, k_lds, v_lds, tid, w);
        __syncthreads();                   // drains vmcnt -> tile t+1 visible
    }
    // ---- write partials: acc (unnormalized, ref = mrun), plus (m, l) ----
    #pragma unroll
    for (int j = 0; j < 2; j++) {
        int n = n_base + j;
        long po = ((long)(b * 8 + mc) * 16 + n) * 256 + m * 8;
        float4 f0, f1;
        f0.x = acc[j*8+0]; f0.y = acc[j*8+1]; f0.z = acc[j*8+2]; f0.w = acc[j*8+3];
        f1.x = acc[j*8+4]; f1.y = acc[j*8+5]; f1.z = acc[j*8+6]; f1.w = acc[j*8+7];
        *reinterpret_cast<float4*>(&part[po]) = f0;
        *reinterpret_cast<float4*>(&part[po + 4]) = f1;
    }
    if (m == 0) {
        int base = ((b * 8 + mc) * 16 + n_base) * 2;
        ml[base + 0] = mrun0; ml[base + 1] = lrun0;
        ml[base + 2] = mrun1; ml[base + 3] = lrun1;
    }
}

// ---------------- fused merge + GRU + LayerNorm + MLP residual + next-q; 2 rows/block ----------------
__global__ __launch_bounds__(256) void k_gru(const float* __restrict__ part, const float* __restrict__ ml,
        float* __restrict__ slots,
        const u32* __restrict__ wgh, const float* __restrict__ b_ih, const float* __restrict__ b_hh,
        const float* __restrict__ ln_g, const float* __restrict__ ln_b,
        const u32* __restrict__ w1p, const float* __restrict__ b1,
        const u32* __restrict__ w2p, const float* __restrict__ b2,
        const u32* __restrict__ wqp, float* __restrict__ qout) {
    __shared__ float u_lds[2][256], s_lds[2][256], h_lds[2][256], hm_lds[2][512], sf_lds[2][256];
    __shared__ float red[2][4][2];
    int t = threadIdx.x;
    int row0 = blockIdx.x * 2;
    int b = row0 >> 4, n0 = row0 & 15;
    // merge flash partials (softmax renormalization across 8 m-chunks)
    #pragma unroll
    for (int rr = 0; rr < 2; rr++) {
        int n = n0 + rr;
        const float* mlp = ml + ((long)b * 128 + n) * 2;
        float mv[8], lv[8];
        #pragma unroll
        for (int c = 0; c < 8; c++) { mv[c] = mlp[c * 32]; lv[c] = mlp[c * 32 + 1]; }
        float M = mv[0];
        #pragma unroll
        for (int c = 1; c < 8; c++) M = fmaxf(M, mv[c]);
        float ec[8], denom = 0.f;
        #pragma unroll
        for (int c = 0; c < 8; c++) { ec[c] = __expf(mv[c] - M); denom += ec[c] * lv[c]; }
        float inv = 1.f / denom;
        float u = 0.f;
        #pragma unroll
        for (int c = 0; c < 8; c++)
            u += part[(((long)b * 8 + c) * 16 + n) * 256 + t] * ec[c];
        u_lds[rr][t] = u * inv;
        s_lds[rr][t] = slots[(long)(row0 + rr) * 256 + t];
    }
    __syncthreads();
    float gxr[2] = {0,0}, gxz[2] = {0,0}, gxn[2] = {0,0};
    float ghr[2] = {0,0}, ghz[2] = {0,0}, ghn[2] = {0,0};
    #pragma unroll 4
    for (int d = 0; d < 256; d++) {
        u32 p0 = wgh[d * 768 + t], p1 = wgh[d * 768 + 256 + t], p2 = wgh[d * 768 + 512 + t];
        float wir = bf_lo(p0), whr = bf_hi(p0);
        float wiz = bf_lo(p1), whz = bf_hi(p1);
        float win = bf_lo(p2), whn = bf_hi(p2);
        #pragma unroll
        for (int rr = 0; rr < 2; rr++) {
            float ud = u_lds[rr][d], sd = s_lds[rr][d];
            gxr[rr] += ud * wir; ghr[rr] += sd * whr;
            gxz[rr] += ud * wiz; ghz[rr] += sd * whz;
            gxn[rr] += ud * win; ghn[rr] += sd * whn;
        }
    }
    float bir = b_ih[t], biz = b_ih[t + 256], bin = b_ih[t + 512];
    float bhr = b_hh[t], bhz = b_hh[t + 256], bhn = b_hh[t + 512];
    float snew[2];
    int wv = t >> 6, lnid = t & 63;
    #pragma unroll
    for (int rr = 0; rr < 2; rr++) {
        float r = 1.f / (1.f + expf(-(gxr[rr] + bir + ghr[rr] + bhr)));
        float z = 1.f / (1.f + expf(-(gxz[rr] + biz + ghz[rr] + bhz)));
        float nn = tanhf(gxn[rr] + bin + r * (ghn[rr] + bhn));
        snew[rr] = (1.f - z) * nn + z * s_lds[rr][t];
        float sm = snew[rr], sq = snew[rr] * snew[rr];
        #pragma unroll
        for (int off = 32; off > 0; off >>= 1) { sm += __shfl_xor(sm, off); sq += __shfl_xor(sq, off); }
        if (lnid == 0) { red[rr][wv][0] = sm; red[rr][wv][1] = sq; }
    }
    __syncthreads();
    float lng = ln_g[t], lnb = ln_b[t];
    #pragma unroll
    for (int rr = 0; rr < 2; rr++) {
        float sm = red[rr][0][0] + red[rr][1][0] + red[rr][2][0] + red[rr][3][0];
        float sq = red[rr][0][1] + red[rr][1][1] + red[rr][2][1] + red[rr][3][1];
        float mu = sm * (1.f / 256.f);
        float var = sq * (1.f / 256.f) - mu * mu;
        float rs = rsqrtf(var + LN_EPS_F);
        h_lds[rr][t] = (snew[rr] - mu) * rs * lng + lnb;
    }
    __syncthreads();
    float m1a[2] = {0,0}, m1b[2] = {0,0};
    #pragma unroll 4
    for (int d = 0; d < 256; d++) {
        u32 wp = w1p[d * 256 + t];
        float wa = bf_lo(wp), wb = bf_hi(wp);
        #pragma unroll
        for (int rr = 0; rr < 2; rr++) { float hd = h_lds[rr][d]; m1a[rr] += hd * wa; m1b[rr] += hd * wb; }
    }
    float b1a = b1[t], b1b = b1[t + 256];
    #pragma unroll
    for (int rr = 0; rr < 2; rr++) {
        float xa = m1a[rr] + b1a, xb = m1b[rr] + b1b;
        hm_lds[rr][t]       = 0.5f * xa * (1.f + erff(xa * 0.70710678118654752f));
        hm_lds[rr][t + 256] = 0.5f * xb * (1.f + erff(xb * 0.70710678118654752f));
    }
    __syncthreads();
    float m2[2] = {0,0};
    #pragma unroll 4
    for (int d2 = 0; d2 < 256; d2++) {
        u32 wp = w2p[d2 * 256 + t];
        #pragma unroll
        for (int rr = 0; rr < 2; rr++)
            m2[rr] += bf_lo(wp) * hm_lds[rr][2*d2] + bf_hi(wp) * hm_lds[rr][2*d2 + 1];
    }
    float b2v = b2[t];
    #pragma unroll
    for (int rr = 0; rr < 2; rr++) {
        float sf = snew[rr] + m2[rr] + b2v;
        slots[(long)(row0 + rr) * 256 + t] = sf;
        sf_lds[rr][t] = sf;
    }
    __syncthreads();
    // q for next iteration (wasted on last iter; keeps work deterministic)
    float qa[2] = {0,0};
    #pragma unroll 4
    for (int d2 = 0; d2 < 128; d2++) {
        u32 wp = wqp[d2 * 256 + t];
        #pragma unroll
        for (int rr = 0; rr < 2; rr++)
            qa[rr] += bf_lo(wp) * sf_lds[rr][2*d2] + bf_hi(wp) * sf_lds[rr][2*d2 + 1];
    }
    #pragma unroll
    for (int rr = 0; rr < 2; rr++)
        qout[(long)(row0 + rr) * 256 + t] = qa[rr] * SCALE_F;
}

extern "C" void kernel_launch(void* const* d_in, const int* in_sizes, int n_in,
                              void* d_out, int out_size, void* d_ws, size_t ws_size,
                              hipStream_t stream) {
    const float* inputs  = (const float*)d_in[0];
    const float* noise   = (const float*)d_in[1];
    const float* slot_mu = (const float*)d_in[2];
    const float* slot_ls = (const float*)d_in[3];
    const float* Wq   = (const float*)d_in[4];
    const float* Wk   = (const float*)d_in[5];
    const float* Wv   = (const float*)d_in[6];
    const float* W_ih = (const float*)d_in[7];
    const float* W_hh = (const float*)d_in[8];
    const float* b_ih = (const float*)d_in[9];
    const float* b_hh = (const float*)d_in[10];
    const float* ln_g = (const float*)d_in[11];
    const float* ln_b = (const float*)d_in[12];
    const float* W1   = (const float*)d_in[13];
    const float* b1   = (const float*)d_in[14];
    const float* W2   = (const float*)d_in[15];
    const float* b2   = (const float*)d_in[16];
    float* slots = (float*)d_out;

    char* ws = (char*)d_ws;
    u16*   kbf  = (u16*)  (ws);                    // 134217728 B
    u16*   vbf  = (u16*)  (ws + 134217728);        // 134217728 B
    float* q    = (float*)(ws + 268435456);        // 1048576 B
    float* part = (float*)(ws + 269484032);        // 8388608 B
    float* ml   = (float*)(ws + 277872640);        // 65536 B
    u16*   w_t  = (u16*)  (ws + 277938176);        // 262144 B
    u32*   wgh  = (u32*)  (ws + 278200320);        // 786432 B
    u32*   wqp  = (u32*)  (ws + 278986752);        // 131072 B
    u32*   w1p  = (u32*)  (ws + 279117824);        // 262144 B
    u32*   w2p  = (u32*)  (ws + 279379968);        // 262144 B

    k_prep<<<dim3(2944), dim3(256), 0, stream>>>(noise, slot_mu, slot_ls, Wq, Wk, Wv,
            W_ih, W_hh, W1, W2, slots, w_t, wqp, wgh, w1p, w2p);
    k_gemm_kv<<<dim3(2048), dim3(512), 0, stream>>>(inputs, w_t, kbf, vbf);
    k_qproj<<<dim3(1024), dim3(256), 0, stream>>>(slots, wqp, q);
    for (int it = 0; it < 3; it++) {
        k_flash<<<dim3(8, 64), dim3(256), 0, stream>>>(q, kbf, vbf, part, ml);
        k_gru<<<dim3(512), dim3(256), 0, stream>>>(part, ml, slots,
                wgh, b_ih, b_hh, ln_g, ln_b, w1p, b1, w2p, b2, wqp, q);
    }
}